// Round 9
// baseline (201.587 us; speedup 1.0000x reference)
//
#include <hip/hip_runtime.h>
#include <cstdint>
#include <cstddef>

// Problem constants (F, H, D, A, B) = (500, 2000, 64, 64, 4096)
#define F_N 500
#define H_N 2000
#define JN  2500   // F + H
#define D_N 64
#define A_N 64
#define B_N 4096

#define SPLIT  2         // blocks per attention row i (partial buffers, no atomics)
#define JCHUNK 1250      // JN / SPLIT
#define NBLK   1000      // fused-kernel grid (all co-resident: 26.7 KB LDS -> 6/CU)

// ---------------------------------------------------------------------------
// Kernel 1: pre_f[i][a] = feat[i,:] @ W1[:,a] + bw[a]   (row-major, 500x64)
//           pre_w[j][a] = full[j,:] @ W2[:,a]           (row-major, 2500x64)
// One wave per row; lane = a. Also zeroes the 2 barrier words (workspace is
// poisoned each iteration by the harness).
// ---------------------------------------------------------------------------
__global__ __launch_bounds__(256) void k_pre(
    const float* __restrict__ feat, const float* __restrict__ hid,
    const float* __restrict__ Ww,   const float* __restrict__ bw,
    float* __restrict__ pre_f, float* __restrict__ pre_w,
    int* __restrict__ bar)
{
    if (blockIdx.x == 0 && threadIdx.x < 2) bar[threadIdx.x] = 0;

    const int lane = threadIdx.x & 63;
    const int wave = threadIdx.x >> 6;
    int row = blockIdx.x * 4 + wave;                   // 0..2999
    row = __builtin_amdgcn_readfirstlane(row);         // force scalar
    if (row >= F_N + JN) return;

    const float* emb;
    const float* W;
    float*       outp;
    float acc0, acc1 = 0.0f;

    if (row < F_N) {                 // pre_f row (bias folded in)
        emb  = feat + (size_t)row * D_N;
        W    = Ww;                   // W1 = Ww[0:64]
        outp = pre_f + (size_t)row * A_N;
        acc0 = bw[lane];
    } else {                         // pre_w row
        const int j = row - F_N;
        emb  = (j < F_N) ? (feat + (size_t)j * D_N)
                         : (hid + (size_t)(j - F_N) * D_N);
        W    = Ww + D_N * A_N;       // W2 = Ww[64:128]
        outp = pre_w + (size_t)j * A_N;
        acc0 = 0.0f;
    }

    #pragma unroll
    for (int d = 0; d < D_N; d += 2) {
        acc0 = fmaf(emb[d],     W[(d    ) * A_N + lane], acc0);  // emb: s_load
        acc1 = fmaf(emb[d + 1], W[(d + 1) * A_N + lane], acc1);
    }
    outp[lane] = acc0 + acc1;        // coalesced row-major store
}

// ---------------------------------------------------------------------------
// Kernel 2 (fused attn+out): 1000 blocks. Attn phase = R6's proven body
// (thread-per-j scores on precomputed pre_w; disjoint csum/esum partials,
// plain stores). Then a grid barrier with the R3 pathology FIXED:
//   R3 spun on ACQUIRE agent-scope loads every ~128 cyc from 512 blocks ->
//   each acquire invalidates that CU's L1 -> co-resident attn blocks lose
//   all L1 hits (3.4x blowup). Here: RELAXED polling (no invalidate),
//   s_sleep(32) (~2k cyc) between polls, ONE acquire load after the flip.
// Blocks >=512 arrive-and-exit. Blocks <512 also warm their values rows
// (barrier-independent) before polling, then run R6's k_out body.
// ---------------------------------------------------------------------------
__global__ __launch_bounds__(256, 4) void k_fused2(
    const float* __restrict__ feat, const float* __restrict__ hid,
    const float* __restrict__ pre_f, const float* __restrict__ pre_w,
    const float* __restrict__ Wu,   const void* __restrict__ mask,
    const float* __restrict__ values,
    float* __restrict__ csum, float* __restrict__ esum,
    float* __restrict__ out,  int* __restrict__ bar)
{
    const int tid  = threadIdx.x;
    const int lane = tid & 63;
    const int wave = tid >> 6;

    __shared__ __align__(16) char smem[25600];
    __shared__ float s_ss[4];
    __shared__ int   nact;

    // =======================================================================
    // Phase 1: attention partials (all 1000 blocks) — R6 body verbatim.
    // =======================================================================
    {
        int*   list = (int*)smem;                            // 5000 B
        float* earr = (float*)(smem + 5120);                 // 5000 B
        float (*s_ctx)[64] = (float (*)[64])(smem + 10240);  // 1024 B

        const int i     = blockIdx.x >> 1;          // 0..499
        const int sub   = blockIdx.x & 1;           // 0..1
        const int jbase = sub * JCHUNK;

        if (tid == 0) nact = 0;
        __syncthreads();

        // --- runtime mask-dtype detection: bool bytes vs int32 -------------
        const uint32_t* mw = (const uint32_t*)mask;
        const uint32_t probe = mw[lane] | mw[64 + lane] | mw[128 + lane] | mw[192 + lane];
        const bool byteMode = (__ballot(probe > 1u) != 0ull);

        const uint8_t*  mb = (const uint8_t*)mask + (size_t)i * JN + jbase;
        const uint32_t* mi = (const uint32_t*)mask + (size_t)i * JN + jbase;

        // --- A: compaction (5 uniform passes) -------------------------------
        for (int t = tid; t < 1280; t += 256) {
            uint32_t m = 0;
            if (t < JCHUNK) m = byteMode ? (uint32_t)mb[t] : mi[t];
            const unsigned long long act = __ballot(m != 0);
            const int cnt = __popcll(act);
            int base = 0;
            if (lane == 0 && cnt) base = atomicAdd(&nact, cnt);
            base = __shfl(base, 0, 64);
            if (m) {
                const int rank = __popcll(act & ((1ull << lane) - 1ull));
                list[base + rank] = jbase + t;     // store GLOBAL j
            }
        }
        __syncthreads();
        const int n = nact;                        // ~125 active

        // --- B: thread-per-j scores on precomputed pre_w (L2-resident) ------
        const float* pf = pre_f + (size_t)i * A_N; // block-uniform -> s_loads
        for (int idx = tid; idx < n; idx += 256) {
            const int j = list[idx];
            const float4* pwj = (const float4*)(pre_w + (size_t)j * A_N);
            float s0 = 0.0f, s1 = 0.0f, s2 = 0.0f, s3 = 0.0f;
            #pragma unroll
            for (int q = 0; q < 16; ++q) {
                const float4 v = pwj[q];
                const int a = q * 4;
                // tanh(x) = 1 - 2/(exp(2x)+1); v_rcp_f32 is plenty accurate
                const float x0 = pf[a + 0] + v.x;
                const float x1 = pf[a + 1] + v.y;
                const float x2 = pf[a + 2] + v.z;
                const float x3 = pf[a + 3] + v.w;
                const float t0 = fmaf(-2.0f, __builtin_amdgcn_rcpf(__expf(2.0f * x0) + 1.0f), 1.0f);
                const float t1 = fmaf(-2.0f, __builtin_amdgcn_rcpf(__expf(2.0f * x1) + 1.0f), 1.0f);
                const float t2 = fmaf(-2.0f, __builtin_amdgcn_rcpf(__expf(2.0f * x2) + 1.0f), 1.0f);
                const float t3 = fmaf(-2.0f, __builtin_amdgcn_rcpf(__expf(2.0f * x3) + 1.0f), 1.0f);
                s0 = fmaf(Wu[a + 0], t0, s0);
                s1 = fmaf(Wu[a + 1], t1, s1);
                s2 = fmaf(Wu[a + 2], t2, s2);
                s3 = fmaf(Wu[a + 3], t3, s3);
            }
            earr[idx] = __expf((s0 + s1) + (s2 + s3));
        }
        __syncthreads();

        // --- C: partial context accumulation (lane = d), 4x unrolled --------
        float cacc = 0.0f;
        int idx = wave;                            // stride 4 per wave
        for (; idx + 12 < n; idx += 16) {
            const float e0 = earr[idx];      const int j0 = list[idx];
            const float e1 = earr[idx + 4];  const int j1 = list[idx + 4];
            const float e2 = earr[idx + 8];  const int j2 = list[idx + 8];
            const float e3 = earr[idx + 12]; const int j3 = list[idx + 12];
            const float* r0 = (j0 < F_N) ? (feat + (size_t)j0 * D_N) : (hid + (size_t)(j0 - F_N) * D_N);
            const float* r1 = (j1 < F_N) ? (feat + (size_t)j1 * D_N) : (hid + (size_t)(j1 - F_N) * D_N);
            const float* r2 = (j2 < F_N) ? (feat + (size_t)j2 * D_N) : (hid + (size_t)(j2 - F_N) * D_N);
            const float* r3 = (j3 < F_N) ? (feat + (size_t)j3 * D_N) : (hid + (size_t)(j3 - F_N) * D_N);
            const float v0 = r0[lane];
            const float v1 = r1[lane];
            const float v2 = r2[lane];
            const float v3 = r3[lane];
            cacc = fmaf(e0, v0, cacc);
            cacc = fmaf(e1, v1, cacc);
            cacc = fmaf(e2, v2, cacc);
            cacc = fmaf(e3, v3, cacc);
        }
        for (; idx < n; idx += 4) {
            const float e = earr[idx];
            const int   j = list[idx];
            const float* row = (j < F_N) ? (feat + (size_t)j * D_N)
                                         : (hid + (size_t)(j - F_N) * D_N);
            cacc = fmaf(e, row[lane], cacc);
        }
        s_ctx[wave][lane] = cacc;
        __syncthreads();

        if (wave == 0) {
            const float c4 = s_ctx[0][lane] + s_ctx[1][lane] + s_ctx[2][lane] + s_ctx[3][lane];
            float ss = 0.0f;
            for (int k = lane; k < n; k += 64) ss += earr[k];
            #pragma unroll
            for (int off = 1; off < 64; off <<= 1) ss += __shfl_xor(ss, off, 64);
            // disjoint partial slots: plain stores, no atomics, no zero-init
            csum[((size_t)sub * F_N + i) * D_N + lane] = c4;
            if (lane == 0) esum[sub * F_N + i] = ss;
        }
    }

    // =======================================================================
    // Grid barrier (relaxed-poll). Arrive: all 1000. Wait: only blocks <512.
    // =======================================================================
    const bool doOut = (blockIdx.x < 512);
    const int  rowB  = blockIdx.x * 8;

    __syncthreads();                               // all block stores done
    if (tid == 0) {
        __threadfence();                           // release csum/esum
        const int old = __hip_atomic_fetch_add(bar + 0, 1, __ATOMIC_ACQ_REL,
                                               __HIP_MEMORY_SCOPE_AGENT);
        if (old == NBLK - 1)
            __hip_atomic_store(bar + 1, 1, __ATOMIC_RELEASE,
                               __HIP_MEMORY_SCOPE_AGENT);
    }
    if (!doOut) return;                            // arrive-only blocks exit

    // ---- warm this block's values rows while others finish (L1/L2 fill) ---
    float warm = 0.0f;
    {
        const float4* vp = (const float4*)(values + (size_t)rowB * 500);
        #pragma unroll
        for (int q = 0; q < 4; ++q) {
            const int t = tid + q * 256;
            if (t < 1000) warm += vp[t].x;
        }
    }
    asm volatile("" :: "v"(warm));                 // keep loads live (rule #17)

    if (tid == 0) {
        // RELAXED poll: no cache-invalidate traffic while attn blocks run
        while (__hip_atomic_load(bar + 1, __ATOMIC_RELAXED,
                                 __HIP_MEMORY_SCOPE_AGENT) == 0) {
            __builtin_amdgcn_s_sleep(32);          // ~2k cycles between polls
        }
        // exactly ONE acquire to publish other blocks' csum/esum
        const int v = __hip_atomic_load(bar + 1, __ATOMIC_ACQUIRE,
                                        __HIP_MEMORY_SCOPE_AGENT);
        if (v == 0) __builtin_amdgcn_s_sleep(1);   // never taken; keeps load
    }
    __syncthreads();

    // =======================================================================
    // Phase 2: out = values @ (Σ csum / guard(Σ esum)) — R6 k_out body.
    // =======================================================================
    {
        float* ctx_l = (float*)smem;                 // 25.6 KB overlay

        int r0 = rowB + wave * 2;                    // wave's first row
        r0 = __builtin_amdgcn_readfirstlane(r0);     // force scalar addressing

        float4 cbuf0[7], cbuf1[7];                   // two partial ctx chunks
        float  ebuf[7];                              // summed esum per slot

        float acc0 = 0.0f, acc1 = 0.0f;

        // ---- prefetch chunk 0 (lane-coalesced) ----
        {
            const float4* cp0 = (const float4*)csum;                       // sub 0
            const float4* cp1 = (const float4*)(csum + (size_t)F_N * D_N); // sub 1
            #pragma unroll
            for (int q = 0; q < 7; ++q) {
                const int t = tid + q * 256;
                if (t < 1600) {
                    cbuf0[q] = cp0[t];
                    cbuf1[q] = cp1[t];
                    ebuf[q]  = esum[t >> 4] + esum[F_N + (t >> 4)];
                }
            }
        }

        for (int chunk = 0; chunk < 5; ++chunk) {
            __syncthreads();                         // LDS free (prev compute done)
            // ---- registers -> LDS: sum partials + normalize ----
            {
                float4* cl = (float4*)ctx_l;
                #pragma unroll
                for (int q = 0; q < 7; ++q) {
                    const int t = tid + q * 256;
                    if (t < 1600) {
                        const float e   = ebuf[q];
                        const float inv = (e == 0.0f) ? 1.0f : __builtin_amdgcn_rcpf(e);
                        float4 c;
                        c.x = (cbuf0[q].x + cbuf1[q].x) * inv;
                        c.y = (cbuf0[q].y + cbuf1[q].y) * inv;
                        c.z = (cbuf0[q].z + cbuf1[q].z) * inv;
                        c.w = (cbuf0[q].w + cbuf1[q].w) * inv;
                        cl[t] = c;
                    }
                }
            }
            __syncthreads();

            // ---- issue prefetch of chunk+1 (loads fly during compute) ----
            if (chunk < 4) {
                const int k0n = (chunk + 1) * 100;
                const float4* cp0 = (const float4*)(csum + (size_t)k0n * 64);
                const float4* cp1 = (const float4*)(csum + (size_t)(F_N + k0n) * 64);
                #pragma unroll
                for (int q = 0; q < 7; ++q) {
                    const int t = tid + q * 256;
                    if (t < 1600) {
                        cbuf0[q] = cp0[t];
                        cbuf1[q] = cp1[t];
                        ebuf[q]  = esum[k0n + (t >> 4)] + esum[F_N + k0n + (t >> 4)];
                    }
                }
            }

            // ---- compute current chunk: ctx from LDS, values via s_loads ----
            const int k0 = chunk * 100;
            const float* v0 = values + (size_t)(r0 + 0) * 500 + k0;  // scalar ptr
            const float* v1 = values + (size_t)(r0 + 1) * 500 + k0;
            #pragma unroll 10
            for (int k = 0; k < 100; k += 4) {
                const float c0 = ctx_l[(k + 0) * 64 + lane];
                const float c1 = ctx_l[(k + 1) * 64 + lane];
                const float c2 = ctx_l[(k + 2) * 64 + lane];
                const float c3 = ctx_l[(k + 3) * 64 + lane];
                acc0 = fmaf(v0[k + 0], c0, acc0); acc0 = fmaf(v0[k + 1], c1, acc0);
                acc0 = fmaf(v0[k + 2], c2, acc0); acc0 = fmaf(v0[k + 3], c3, acc0);
                acc1 = fmaf(v1[k + 0], c0, acc1); acc1 = fmaf(v1[k + 1], c1, acc1);
                acc1 = fmaf(v1[k + 2], c2, acc1); acc1 = fmaf(v1[k + 3], c3, acc1);
            }
        }

        out[(size_t)(r0 + 0) * 64 + lane] = acc0;    // coalesced 256 B per wave
        out[(size_t)(r0 + 1) * 64 + lane] = acc1;
    }
}

// ---------------------------------------------------------------------------
extern "C" void kernel_launch(void* const* d_in, const int* in_sizes, int n_in,
                              void* d_out, int out_size, void* d_ws, size_t ws_size,
                              hipStream_t stream)
{
    const float* values = (const float*)d_in[0];   // (4096, 500)
    const float* feat   = (const float*)d_in[1];   // (500, 64)
    const float* hid    = (const float*)d_in[2];   // (2000, 64)
    const float* Ww     = (const float*)d_in[3];   // (128, 64)
    const float* bw     = (const float*)d_in[4];   // (64,)
    const float* Wu     = (const float*)d_in[5];   // (64, 1)
    const void*  mask   = d_in[6];                 // (500, 2500, 1) — dtype detected on device
    float* out = (float*)d_out;                    // (4096, 64)

    // Workspace layout (floats):
    //   pre_f[32000] | pre_w[160000] | csum[2*32000] | esum[2*500] | bar[2]
    float* wsf   = (float*)d_ws;
    float* pre_f = wsf;                  // 32000 floats
    float* pre_w = wsf + 32000;          // 160000 floats (row-major 2500 x 64)
    float* csum  = wsf + 192000;         // 64000 floats (2 partial buffers)
    float* esum  = wsf + 256000;         // 1000 floats  (2 partial buffers)
    int*   bar   = (int*)(wsf + 257000); // 2 ints (zeroed by k_pre)

    k_pre   <<<750,  256, 0, stream>>>(feat, hid, Ww, bw, pre_f, pre_w, bar);
    k_fused2<<<NBLK, 256, 0, stream>>>(feat, hid, pre_f, pre_w, Wu, mask,
                                       values, csum, esum, out, bar);
}

// Round 10
// 124.664 us; speedup vs baseline: 1.6170x; 1.6170x over previous
//
#include <hip/hip_runtime.h>
#include <cstdint>
#include <cstddef>

// Problem constants (F, H, D, A, B) = (500, 2000, 64, 64, 4096)
#define F_N 500
#define H_N 2000
#define JN  2500   // F + H
#define D_N 64
#define A_N 64
#define B_N 4096

#define SPLIT  2         // blocks per attention row i (partial buffers, no atomics)
#define JCHUNK 1250      // JN / SPLIT

// ---------------------------------------------------------------------------
// Kernel 1: pre_f[i][a] = feat[i,:] @ W1[:,a] + bw[a]   (row-major, 500x64)
//           pre_w[j][a] = full[j,:] @ W2[:,a]           (row-major, 2500x64)
// One wave per row; lane = a. No zeroing (partial buffers are plain-stored).
// ---------------------------------------------------------------------------
__global__ __launch_bounds__(256) void k_pre(
    const float* __restrict__ feat, const float* __restrict__ hid,
    const float* __restrict__ Ww,   const float* __restrict__ bw,
    float* __restrict__ pre_f, float* __restrict__ pre_w)
{
    const int lane = threadIdx.x & 63;
    const int wave = threadIdx.x >> 6;
    int row = blockIdx.x * 4 + wave;                   // 0..2999
    row = __builtin_amdgcn_readfirstlane(row);         // force scalar
    if (row >= F_N + JN) return;

    const float* emb;
    const float* W;
    float*       outp;
    float acc0, acc1 = 0.0f;

    if (row < F_N) {                 // pre_f row (bias folded in)
        emb  = feat + (size_t)row * D_N;
        W    = Ww;                   // W1 = Ww[0:64]
        outp = pre_f + (size_t)row * A_N;
        acc0 = bw[lane];
    } else {                         // pre_w row
        const int j = row - F_N;
        emb  = (j < F_N) ? (feat + (size_t)j * D_N)
                         : (hid + (size_t)(j - F_N) * D_N);
        W    = Ww + D_N * A_N;       // W2 = Ww[64:128]
        outp = pre_w + (size_t)j * A_N;
        acc0 = 0.0f;
    }

    #pragma unroll
    for (int d = 0; d < D_N; d += 2) {
        acc0 = fmaf(emb[d],     W[(d    ) * A_N + lane], acc0);  // emb: s_load
        acc1 = fmaf(emb[d + 1], W[(d + 1) * A_N + lane], acc1);
    }
    outp[lane] = acc0 + acc1;        // coalesced row-major store
}

// ---------------------------------------------------------------------------
// Kernel 2: attention partials, 1000 blocks (i = b/2, j-half b&1).
// R9 diagnosis: thread-per-j scoring made every pre_w load a 64-way
// address-divergent gather (~60 cache lines PER INSTRUCTION; ~256 MB of
// L1<-L2 line traffic kernel-wide). Phase B is now WAVE-PER-J:
//   all 64 lanes load pre_w[j][lane]   -> ONE coalesced 256B transaction
//   lane a: t = tanh(pf[a] + v), m = Wu[a]*t
//   6-step shfl_xor allreduce -> score; exp once; all 4 waves busy.
// Same FLOPs, ~16x fewer L2 transactions. Everything else = R6 verbatim:
// no atomics, no zero-init, disjoint csum[sub][i][d]/esum[sub][i] stores.
// ---------------------------------------------------------------------------
__global__ __launch_bounds__(256, 8) void k_attn(
    const float* __restrict__ feat, const float* __restrict__ hid,
    const float* __restrict__ pre_f, const float* __restrict__ pre_w,
    const float* __restrict__ Wu,   const void* __restrict__ mask,
    float* __restrict__ csum, float* __restrict__ esum)
{
    const int tid  = threadIdx.x;
    const int lane = tid & 63;
    const int wave = tid >> 6;
    const int i    = blockIdx.x >> 1;          // 0..499
    const int sub  = blockIdx.x & 1;           // 0..1
    const int jbase = sub * JCHUNK;

    __shared__ int   list[JCHUNK];
    __shared__ float earr[JCHUNK];
    __shared__ float s_ctx[4][64];
    __shared__ float s_ss[4];
    __shared__ int   nact;

    if (tid == 0) nact = 0;
    __syncthreads();

    // --- runtime mask-dtype detection: bool bytes vs int32 -----------------
    const uint32_t* mw = (const uint32_t*)mask;
    const uint32_t probe = mw[lane] | mw[64 + lane] | mw[128 + lane] | mw[192 + lane];
    const bool byteMode = (__ballot(probe > 1u) != 0ull);

    const uint8_t*  mb = (const uint8_t*)mask + (size_t)i * JN + jbase;
    const uint32_t* mi = (const uint32_t*)mask + (size_t)i * JN + jbase;

    // --- A: compaction over this block's 1250 j's (5 uniform passes) --------
    for (int t = tid; t < 1280; t += 256) {
        uint32_t m = 0;
        if (t < JCHUNK) m = byteMode ? (uint32_t)mb[t] : mi[t];
        const unsigned long long act = __ballot(m != 0);
        const int cnt = __popcll(act);
        int base = 0;
        if (lane == 0 && cnt) base = atomicAdd(&nact, cnt);
        base = __shfl(base, 0, 64);
        if (m) {
            const int rank = __popcll(act & ((1ull << lane) - 1ull));
            list[base + rank] = jbase + t;     // store GLOBAL j
        }
    }
    __syncthreads();
    const int n = nact;                        // ~125 active

    // --- B: wave-per-j scores (coalesced pre_w reads) -----------------------
    const float pf = pre_f[(size_t)i * A_N + lane];   // hoisted, coalesced
    const float wu = Wu[lane];
    float ss_w = 0.0f;
    for (int pos = wave; pos < n; pos += 4) {
        const int j = __builtin_amdgcn_readfirstlane(list[pos]);  // uniform
        const float v = pre_w[(size_t)j * A_N + lane];            // 256B coalesced
        const float x = pf + v;
        // tanh(x) = 1 - 2/(exp(2x)+1); v_rcp_f32 is plenty accurate here
        const float t = fmaf(-2.0f, __builtin_amdgcn_rcpf(__expf(2.0f * x) + 1.0f), 1.0f);
        float m = wu * t;                      // Wu[a] * tanh(.)
        #pragma unroll
        for (int off = 1; off < 64; off <<= 1) m += __shfl_xor(m, off, 64);
        const float e = __expf(m);             // allreduce -> all lanes hold e
        if (lane == 0) earr[pos] = e;
        ss_w += e;                             // lane-redundant accumulate
    }
    if (lane == 0) s_ss[wave] = ss_w;
    __syncthreads();

    // --- C: partial context accumulation (lane = d), 4x unrolled ------------
    float cacc = 0.0f;
    int idx = wave;                            // stride 4 per wave
    for (; idx + 12 < n; idx += 16) {
        const float e0 = earr[idx];      const int j0 = list[idx];
        const float e1 = earr[idx + 4];  const int j1 = list[idx + 4];
        const float e2 = earr[idx + 8];  const int j2 = list[idx + 8];
        const float e3 = earr[idx + 12]; const int j3 = list[idx + 12];
        const float* r0 = (j0 < F_N) ? (feat + (size_t)j0 * D_N) : (hid + (size_t)(j0 - F_N) * D_N);
        const float* r1 = (j1 < F_N) ? (feat + (size_t)j1 * D_N) : (hid + (size_t)(j1 - F_N) * D_N);
        const float* r2 = (j2 < F_N) ? (feat + (size_t)j2 * D_N) : (hid + (size_t)(j2 - F_N) * D_N);
        const float* r3 = (j3 < F_N) ? (feat + (size_t)j3 * D_N) : (hid + (size_t)(j3 - F_N) * D_N);
        const float v0 = r0[lane];
        const float v1 = r1[lane];
        const float v2 = r2[lane];
        const float v3 = r3[lane];
        cacc = fmaf(e0, v0, cacc);
        cacc = fmaf(e1, v1, cacc);
        cacc = fmaf(e2, v2, cacc);
        cacc = fmaf(e3, v3, cacc);
    }
    for (; idx < n; idx += 4) {
        const float e = earr[idx];
        const int   j = list[idx];
        const float* row = (j < F_N) ? (feat + (size_t)j * D_N)
                                     : (hid + (size_t)(j - F_N) * D_N);
        cacc = fmaf(e, row[lane], cacc);
    }
    s_ctx[wave][lane] = cacc;
    __syncthreads();

    if (wave == 0) {
        const float c4 = s_ctx[0][lane] + s_ctx[1][lane] + s_ctx[2][lane] + s_ctx[3][lane];
        const float ss = s_ss[0] + s_ss[1] + s_ss[2] + s_ss[3];
        // disjoint partial slots: plain stores, no atomics, no zero-init
        csum[((size_t)sub * F_N + i) * D_N + lane] = c4;
        if (lane == 0) esum[sub * F_N + i] = ss;
    }
}

// ---------------------------------------------------------------------------
// Kernel 3: out = values (4096x500) @ ctx, where ctx[i][d] =
// (csum[0][i][d]+csum[1][i][d]) / guard(esum[0][i]+esum[1][i]).
// 512 blocks x 256 thr, 8 rows/block (2 rows/wave). Partial summation +
// normalization (incl. ssum==0 -> 1 guard) folded into the LDS staging;
// register-prefetch of chunk c+1 overlaps compute. values rows read as
// wave-uniform s_loads (readfirstlane'd row); ctx reads per-lane b32.
// ---------------------------------------------------------------------------
__global__ __launch_bounds__(256) void k_out(
    const float* __restrict__ values, const float* __restrict__ csum,
    const float* __restrict__ esum,   float* __restrict__ out)
{
    const int tid  = threadIdx.x;
    const int lane = tid & 63;
    const int wave = tid >> 6;
    int r0 = blockIdx.x * 8 + wave * 2;          // wave's first row
    r0 = __builtin_amdgcn_readfirstlane(r0);     // force scalar addressing

    __shared__ float ctx_l[100 * 64];            // 25.6 KB

    float4 cbuf0[7], cbuf1[7];                   // two partial ctx chunks
    float  ebuf[7];                              // summed esum per slot

    float acc0 = 0.0f, acc1 = 0.0f;

    // ---- prefetch chunk 0 (lane-coalesced) ----
    {
        const float4* cp0 = (const float4*)csum;                       // sub 0
        const float4* cp1 = (const float4*)(csum + (size_t)F_N * D_N); // sub 1
        #pragma unroll
        for (int q = 0; q < 7; ++q) {
            const int t = tid + q * 256;
            if (t < 1600) {
                cbuf0[q] = cp0[t];
                cbuf1[q] = cp1[t];
                ebuf[q]  = esum[t >> 4] + esum[F_N + (t >> 4)];
            }
        }
    }

    for (int chunk = 0; chunk < 5; ++chunk) {
        __syncthreads();                         // LDS free (prev compute done)
        // ---- registers -> LDS: sum partials + normalize ----
        {
            float4* cl = (float4*)ctx_l;
            #pragma unroll
            for (int q = 0; q < 7; ++q) {
                const int t = tid + q * 256;
                if (t < 1600) {
                    const float e   = ebuf[q];
                    const float inv = (e == 0.0f) ? 1.0f : __builtin_amdgcn_rcpf(e);
                    float4 c;
                    c.x = (cbuf0[q].x + cbuf1[q].x) * inv;
                    c.y = (cbuf0[q].y + cbuf1[q].y) * inv;
                    c.z = (cbuf0[q].z + cbuf1[q].z) * inv;
                    c.w = (cbuf0[q].w + cbuf1[q].w) * inv;
                    cl[t] = c;
                }
            }
        }
        __syncthreads();

        // ---- issue prefetch of chunk+1 (loads fly during compute) ----
        if (chunk < 4) {
            const int k0n = (chunk + 1) * 100;
            const float4* cp0 = (const float4*)(csum + (size_t)k0n * 64);
            const float4* cp1 = (const float4*)(csum + (size_t)(F_N + k0n) * 64);
            #pragma unroll
            for (int q = 0; q < 7; ++q) {
                const int t = tid + q * 256;
                if (t < 1600) {
                    cbuf0[q] = cp0[t];
                    cbuf1[q] = cp1[t];
                    ebuf[q]  = esum[k0n + (t >> 4)] + esum[F_N + k0n + (t >> 4)];
                }
            }
        }

        // ---- compute current chunk: ctx from LDS, values via s_loads ----
        const int k0 = chunk * 100;
        const float* v0 = values + (size_t)(r0 + 0) * 500 + k0;  // scalar ptr
        const float* v1 = values + (size_t)(r0 + 1) * 500 + k0;
        #pragma unroll 10
        for (int k = 0; k < 100; k += 4) {
            const float c0 = ctx_l[(k + 0) * 64 + lane];
            const float c1 = ctx_l[(k + 1) * 64 + lane];
            const float c2 = ctx_l[(k + 2) * 64 + lane];
            const float c3 = ctx_l[(k + 3) * 64 + lane];
            acc0 = fmaf(v0[k + 0], c0, acc0); acc0 = fmaf(v0[k + 1], c1, acc0);
            acc0 = fmaf(v0[k + 2], c2, acc0); acc0 = fmaf(v0[k + 3], c3, acc0);
            acc1 = fmaf(v1[k + 0], c0, acc1); acc1 = fmaf(v1[k + 1], c1, acc1);
            acc1 = fmaf(v1[k + 2], c2, acc1); acc1 = fmaf(v1[k + 3], c3, acc1);
        }
    }

    out[(size_t)(r0 + 0) * 64 + lane] = acc0;    // coalesced 256 B per wave
    out[(size_t)(r0 + 1) * 64 + lane] = acc1;
}

// ---------------------------------------------------------------------------
extern "C" void kernel_launch(void* const* d_in, const int* in_sizes, int n_in,
                              void* d_out, int out_size, void* d_ws, size_t ws_size,
                              hipStream_t stream)
{
    const float* values = (const float*)d_in[0];   // (4096, 500)
    const float* feat   = (const float*)d_in[1];   // (500, 64)
    const float* hid    = (const float*)d_in[2];   // (2000, 64)
    const float* Ww     = (const float*)d_in[3];   // (128, 64)
    const float* bw     = (const float*)d_in[4];   // (64,)
    const float* Wu     = (const float*)d_in[5];   // (64, 1)
    const void*  mask   = d_in[6];                 // (500, 2500, 1) — dtype detected on device
    float* out = (float*)d_out;                    // (4096, 64)

    // Workspace layout (floats):
    //   pre_f[32000] | pre_w[160000] | csum[2*32000] | esum[2*500]
    float* wsf   = (float*)d_ws;
    float* pre_f = wsf;                  // 32000 floats
    float* pre_w = wsf + 32000;          // 160000 floats (row-major 2500 x 64)
    float* csum  = wsf + 192000;         // 64000 floats  (2 partial buffers)
    float* esum  = wsf + 256000;         // 1000 floats   (2 partial buffers)

    k_pre <<<750,  256, 0, stream>>>(feat, hid, Ww, bw, pre_f, pre_w);
    k_attn<<<1000, 256, 0, stream>>>(feat, hid, pre_f, pre_w, Wu, mask, csum, esum);
    k_out <<<512,  256, 0, stream>>>(values, csum, esum, out);
}

// Round 11
// 109.963 us; speedup vs baseline: 1.8332x; 1.1337x over previous
//
#include <hip/hip_runtime.h>
#include <cstdint>
#include <cstddef>

// Problem constants (F, H, D, A, B) = (500, 2000, 64, 64, 4096)
#define F_N 500
#define H_N 2000
#define JN  2500   // F + H
#define D_N 64
#define A_N 64
#define B_N 4096

#define SPLIT  2         // blocks per attention row i
#define JCHUNK 1250      // JN / SPLIT

// ---------------------------------------------------------------------------
// R11 = R2 verbatim (best measured: 108.8 us). Session conclusions baked in:
//  - 3-kernel structure; dispatch boundaries are CHEAPER than any in-kernel
//    grid barrier on gfx950 (R1/R3/R9: fused+barrier = 115-180 us alone).
//  - thread-per-j scoring beats wave-per-j (R10: shfl-chain serialization).
//  - body micro-variants (SPLIT, atomics vs partial buffers, dep-chain
//    splitting) are all within noise (R2/R4/R6: 108.8/110.4/113.6).
// ---------------------------------------------------------------------------
__global__ __launch_bounds__(256) void k_pre(
    const float* __restrict__ feat, const float* __restrict__ hid,
    const float* __restrict__ Ww,   const float* __restrict__ bw,
    float* __restrict__ pre_f, float* __restrict__ pre_w,
    float* __restrict__ zero_region)   // csum[32000] | esum[512], contiguous
{
    const int gt = blockIdx.x * 256 + threadIdx.x;
    if (gt < 32512) zero_region[gt] = 0.0f;

    const int lane = threadIdx.x & 63;
    const int wave = threadIdx.x >> 6;
    int row = blockIdx.x * 4 + wave;                   // 0..2999
    row = __builtin_amdgcn_readfirstlane(row);         // force scalar
    if (row >= F_N + JN) return;

    const float* emb;
    const float* W;
    float*       outp;
    float acc0, acc1 = 0.0f;

    if (row < F_N) {                 // pre_f row (bias folded in)
        emb  = feat + (size_t)row * D_N;
        W    = Ww;                   // W1 = Ww[0:64]
        outp = pre_f + (size_t)row * A_N;
        acc0 = bw[lane];
    } else {                         // pre_w row
        const int j = row - F_N;
        emb  = (j < F_N) ? (feat + (size_t)j * D_N)
                         : (hid + (size_t)(j - F_N) * D_N);
        W    = Ww + D_N * A_N;       // W2 = Ww[64:128]
        outp = pre_w + (size_t)j * A_N;
        acc0 = 0.0f;
    }

    #pragma unroll
    for (int d = 0; d < D_N; d += 2) {
        acc0 = fmaf(emb[d],     W[(d    ) * A_N + lane], acc0);  // emb: s_load
        acc1 = fmaf(emb[d + 1], W[(d + 1) * A_N + lane], acc1);
    }
    outp[lane] = acc0 + acc1;        // coalesced row-major store
}

// ---------------------------------------------------------------------------
// Kernel 2: attention partials. Grid = 1000 blocks: block b handles
// i = b/2, j-range [ (b&1)*1250, (b&1)*1250+1250 ).
// Phases: compaction (ballot) -> per-thread score (tanh MLP) -> partial
// context sum. Partials accumulate into global csum[i][d] / esum[i] via
// float atomicAdd (device scope). Normalization happens in k_out.
// ---------------------------------------------------------------------------
__global__ __launch_bounds__(256) void k_attn(
    const float* __restrict__ feat, const float* __restrict__ hid,
    const float* __restrict__ pre_f, const float* __restrict__ pre_w,
    const float* __restrict__ Wu,   const void* __restrict__ mask,
    float* __restrict__ csum, float* __restrict__ esum)
{
    const int tid  = threadIdx.x;
    const int lane = tid & 63;
    const int wave = tid >> 6;
    const int i    = blockIdx.x >> 1;          // 0..499
    const int sub  = blockIdx.x & 1;           // 0..1
    const int jbase = sub * JCHUNK;

    __shared__ int   list[JCHUNK];
    __shared__ float earr[JCHUNK];
    __shared__ float s_ctx[4][64];
    __shared__ int   nact;

    if (tid == 0) nact = 0;
    __syncthreads();

    // --- runtime mask-dtype detection: bool bytes vs int32 -----------------
    const uint32_t* mw = (const uint32_t*)mask;
    const uint32_t probe = mw[lane] | mw[64 + lane] | mw[128 + lane] | mw[192 + lane];
    const bool byteMode = (__ballot(probe > 1u) != 0ull);

    const uint8_t*  mb = (const uint8_t*)mask + (size_t)i * JN + jbase;
    const uint32_t* mi = (const uint32_t*)mask + (size_t)i * JN + jbase;

    // --- A: compaction over this block's 1250 j's (5 uniform passes) --------
    for (int t = tid; t < 1280; t += 256) {
        uint32_t m = 0;
        if (t < JCHUNK) m = byteMode ? (uint32_t)mb[t] : mi[t];
        const unsigned long long act = __ballot(m != 0);
        const int cnt = __popcll(act);
        int base = 0;
        if (lane == 0 && cnt) base = atomicAdd(&nact, cnt);
        base = __shfl(base, 0, 64);
        if (m) {
            const int rank = __popcll(act & ((1ull << lane) - 1ull));
            list[base + rank] = jbase + t;     // store GLOBAL j
        }
    }
    __syncthreads();
    const int n = nact;                        // ~125 active

    // --- B: per-thread score for one active j (row-major, L2-resident) -----
    const float* pf = pre_f + (size_t)i * A_N; // block-uniform -> s_loads
    for (int idx = tid; idx < n; idx += 256) {
        const int j = list[idx];
        const float4* pwj = (const float4*)(pre_w + (size_t)j * A_N); // 256B-aligned
        float s = 0.0f;
        #pragma unroll
        for (int q = 0; q < 16; ++q) {
            const float4 v = pwj[q];
            const int a = q * 4;
            // tanh(x) = 1 - 2/(exp(2x)+1); v_rcp_f32 is plenty accurate here
            const float x0 = pf[a + 0] + v.x;
            const float x1 = pf[a + 1] + v.y;
            const float x2 = pf[a + 2] + v.z;
            const float x3 = pf[a + 3] + v.w;
            const float t0 = fmaf(-2.0f, __builtin_amdgcn_rcpf(__expf(2.0f * x0) + 1.0f), 1.0f);
            const float t1 = fmaf(-2.0f, __builtin_amdgcn_rcpf(__expf(2.0f * x1) + 1.0f), 1.0f);
            const float t2 = fmaf(-2.0f, __builtin_amdgcn_rcpf(__expf(2.0f * x2) + 1.0f), 1.0f);
            const float t3 = fmaf(-2.0f, __builtin_amdgcn_rcpf(__expf(2.0f * x3) + 1.0f), 1.0f);
            s = fmaf(Wu[a + 0], t0, s);
            s = fmaf(Wu[a + 1], t1, s);
            s = fmaf(Wu[a + 2], t2, s);
            s = fmaf(Wu[a + 3], t3, s);
        }
        earr[idx] = __expf(s);
    }
    __syncthreads();

    // --- C: partial context accumulation (lane = d), 4x unrolled ------------
    float cacc = 0.0f;
    int idx = wave;                                    // stride 4 per wave
    for (; idx + 12 < n; idx += 16) {
        const float e0 = earr[idx];      const int j0 = list[idx];
        const float e1 = earr[idx + 4];  const int j1 = list[idx + 4];
        const float e2 = earr[idx + 8];  const int j2 = list[idx + 8];
        const float e3 = earr[idx + 12]; const int j3 = list[idx + 12];
        const float* r0 = (j0 < F_N) ? (feat + (size_t)j0 * D_N) : (hid + (size_t)(j0 - F_N) * D_N);
        const float* r1 = (j1 < F_N) ? (feat + (size_t)j1 * D_N) : (hid + (size_t)(j1 - F_N) * D_N);
        const float* r2 = (j2 < F_N) ? (feat + (size_t)j2 * D_N) : (hid + (size_t)(j2 - F_N) * D_N);
        const float* r3 = (j3 < F_N) ? (feat + (size_t)j3 * D_N) : (hid + (size_t)(j3 - F_N) * D_N);
        const float v0 = r0[lane];
        const float v1 = r1[lane];
        const float v2 = r2[lane];
        const float v3 = r3[lane];
        cacc = fmaf(e0, v0, cacc);
        cacc = fmaf(e1, v1, cacc);
        cacc = fmaf(e2, v2, cacc);
        cacc = fmaf(e3, v3, cacc);
    }
    for (; idx < n; idx += 4) {
        const float e = earr[idx];
        const int   j = list[idx];
        const float* row = (j < F_N) ? (feat + (size_t)j * D_N)
                                     : (hid + (size_t)(j - F_N) * D_N);
        cacc = fmaf(e, row[lane], cacc);
    }
    s_ctx[wave][lane] = cacc;
    __syncthreads();

    if (wave == 0) {
        const float c4 = s_ctx[0][lane] + s_ctx[1][lane] + s_ctx[2][lane] + s_ctx[3][lane];
        float ss = 0.0f;
        for (int k = lane; k < n; k += 64) ss += earr[k];
        #pragma unroll
        for (int off = 1; off < 64; off <<= 1) ss += __shfl_xor(ss, off, 64);
        atomicAdd(&csum[(size_t)i * D_N + lane], c4);   // 64 lanes, distinct addrs
        if (lane == 0) atomicAdd(&esum[i], ss);
    }
}

// ---------------------------------------------------------------------------
// Kernel 3: out = values (4096x500) @ (csum/esum) (500x64).
// 512 blocks x 256 thr, 8 rows/block (2 rows/wave). ctx chunk (100 rows)
// staged to LDS with the esum normalization (and the ssum==0 -> 1 guard)
// applied at store time; register-prefetch of chunk c+1 overlaps compute.
// values rows read as wave-uniform s_loads (readfirstlane'd row); ctx reads
// per-lane conflict-free b32.
// ---------------------------------------------------------------------------
__global__ __launch_bounds__(256) void k_out(
    const float* __restrict__ values, const float* __restrict__ csum,
    const float* __restrict__ esum,   float* __restrict__ out)
{
    const int tid  = threadIdx.x;
    const int lane = tid & 63;
    const int wave = tid >> 6;
    int r0 = blockIdx.x * 8 + wave * 2;          // wave's first row
    r0 = __builtin_amdgcn_readfirstlane(r0);     // force scalar addressing

    __shared__ float ctx_l[100 * 64];            // 25.6 KB

    float4 cbuf[7];                              // ctx chunk: 1600 float4 / 256 thr
    float  ebuf[7];                              // matching esum values

    float acc0 = 0.0f, acc1 = 0.0f;

    // ---- prefetch chunk 0 (lane-coalesced) ----
    {
        const float4* cp = (const float4*)csum;  // k0 = 0
        #pragma unroll
        for (int q = 0; q < 7; ++q) {
            const int t = tid + q * 256;
            if (t < 1600) { cbuf[q] = cp[t]; ebuf[q] = esum[t >> 4]; }
        }
    }

    for (int chunk = 0; chunk < 5; ++chunk) {
        __syncthreads();                         // LDS free (prev compute done)
        // ---- registers -> LDS with normalization ----
        {
            float4* cl = (float4*)ctx_l;
            #pragma unroll
            for (int q = 0; q < 7; ++q) {
                const int t = tid + q * 256;
                if (t < 1600) {
                    const float e   = ebuf[q];
                    const float inv = (e == 0.0f) ? 1.0f : __builtin_amdgcn_rcpf(e);
                    float4 c = cbuf[q];
                    c.x *= inv; c.y *= inv; c.z *= inv; c.w *= inv;
                    cl[t] = c;
                }
            }
        }
        __syncthreads();

        // ---- issue prefetch of chunk+1 (loads fly during compute) ----
        if (chunk < 4) {
            const int k0n = (chunk + 1) * 100;
            const float4* cp = (const float4*)(csum + (size_t)k0n * 64);
            #pragma unroll
            for (int q = 0; q < 7; ++q) {
                const int t = tid + q * 256;
                if (t < 1600) { cbuf[q] = cp[t]; ebuf[q] = esum[k0n + (t >> 4)]; }
            }
        }

        // ---- compute current chunk: ctx from LDS, values via s_loads ----
        const int k0 = chunk * 100;
        const float* v0 = values + (size_t)(r0 + 0) * 500 + k0;  // scalar ptr
        const float* v1 = values + (size_t)(r0 + 1) * 500 + k0;
        #pragma unroll 10
        for (int k = 0; k < 100; k += 4) {
            const float c0 = ctx_l[(k + 0) * 64 + lane];
            const float c1 = ctx_l[(k + 1) * 64 + lane];
            const float c2 = ctx_l[(k + 2) * 64 + lane];
            const float c3 = ctx_l[(k + 3) * 64 + lane];
            acc0 = fmaf(v0[k + 0], c0, acc0); acc0 = fmaf(v0[k + 1], c1, acc0);
            acc0 = fmaf(v0[k + 2], c2, acc0); acc0 = fmaf(v0[k + 3], c3, acc0);
            acc1 = fmaf(v1[k + 0], c0, acc1); acc1 = fmaf(v1[k + 1], c1, acc1);
            acc1 = fmaf(v1[k + 2], c2, acc1); acc1 = fmaf(v1[k + 3], c3, acc1);
        }
    }

    out[(size_t)(r0 + 0) * 64 + lane] = acc0;    // coalesced 256 B per wave
    out[(size_t)(r0 + 1) * 64 + lane] = acc1;
}

// ---------------------------------------------------------------------------
extern "C" void kernel_launch(void* const* d_in, const int* in_sizes, int n_in,
                              void* d_out, int out_size, void* d_ws, size_t ws_size,
                              hipStream_t stream)
{
    const float* values = (const float*)d_in[0];   // (4096, 500)
    const float* feat   = (const float*)d_in[1];   // (500, 64)
    const float* hid    = (const float*)d_in[2];   // (2000, 64)
    const float* Ww     = (const float*)d_in[3];   // (128, 64)
    const float* bw     = (const float*)d_in[4];   // (64,)
    const float* Wu     = (const float*)d_in[5];   // (64, 1)
    const void*  mask   = d_in[6];                 // (500, 2500, 1) — dtype detected on device
    float* out = (float*)d_out;                    // (4096, 64)

    // Workspace layout (floats):
    //   pre_f[32000] | pre_w[160000] | csum[32000] | esum[512]
    float* wsf   = (float*)d_ws;
    float* pre_f = wsf;                  // 32000 floats
    float* pre_w = wsf + 32000;          // 160000 floats (row-major 2500 x 64)
    float* csum  = wsf + 192000;         // 32000 floats (zeroed by k_pre)
    float* esum  = wsf + 224000;         // 512 floats   (zeroed by k_pre)

    k_pre <<<750,  256, 0, stream>>>(feat, hid, Ww, bw, pre_f, pre_w, csum);
    k_attn<<<1000, 256, 0, stream>>>(feat, hid, pre_f, pre_w, Wu, mask, csum, esum);
    k_out <<<512,  256, 0, stream>>>(values, csum, esum, out);
}